// Round 4
// baseline (178.515 us; speedup 1.0000x reference)
//
#include <hip/hip_runtime.h>

namespace {
constexpr int S = 1024, I = 512, C = 8, H = 8;
constexpr float LNEPS = 1e-5f;
constexpr float SCALE = 0.35355339059327373f; // 8^-0.5
constexpr int CH = 128;                       // s-chunks (rows/thread = S/CH = 8)
}

// ---- packed float2 helpers (compiler should emit v_pk_* on gfx950) ----
__device__ __forceinline__ float2 pfma(float2 a, float s, float2 c) {
    return make_float2(fmaf(a.x, s, c.x), fmaf(a.y, s, c.y));
}
__device__ __forceinline__ float2 pmul(float2 a, float2 b) {
    return make_float2(a.x * b.x, a.y * b.y);
}
__device__ __forceinline__ float2 pmuls(float2 a, float s) {
    return make_float2(a.x * s, a.y * s);
}

__device__ __forceinline__ void ln8(const float4 a, const float4 b,
                                    const float gm[8], const float bt[8],
                                    float x[8]) {
    x[0] = a.x; x[1] = a.y; x[2] = a.z; x[3] = a.w;
    x[4] = b.x; x[5] = b.y; x[6] = b.z; x[7] = b.w;
    float mu = 0.f;
#pragma unroll
    for (int c = 0; c < 8; c++) mu += x[c];
    mu *= 0.125f;
    float var = 0.f;
#pragma unroll
    for (int c = 0; c < 8; c++) { float d = x[c] - mu; var += d * d; }
    var *= 0.125f;
    float inv = rsqrtf(var + LNEPS);
#pragma unroll
    for (int c = 0; c < 8; c++) x[c] = (x[c] - mu) * inv * gm[c] + bt[c];
}

// packed LN on a row pair (x2[c].x = row0, x2[c].y = row1)
__device__ __forceinline__ void ln8x2(const float4 a0, const float4 b0,
                                      const float4 a1, const float4 b1,
                                      const float gm[8], const float bt[8],
                                      float2 x2[8]) {
    x2[0] = make_float2(a0.x, a1.x); x2[1] = make_float2(a0.y, a1.y);
    x2[2] = make_float2(a0.z, a1.z); x2[3] = make_float2(a0.w, a1.w);
    x2[4] = make_float2(b0.x, b1.x); x2[5] = make_float2(b0.y, b1.y);
    x2[6] = make_float2(b0.z, b1.z); x2[7] = make_float2(b0.w, b1.w);
    float2 mu = make_float2(0.f, 0.f);
#pragma unroll
    for (int c = 0; c < 8; c++) { mu.x += x2[c].x; mu.y += x2[c].y; }
    mu = pmuls(mu, 0.125f);
    float2 var = make_float2(0.f, 0.f);
#pragma unroll
    for (int c = 0; c < 8; c++) {
        float2 d = make_float2(x2[c].x - mu.x, x2[c].y - mu.y);
        var.x += d.x * d.x; var.y += d.y * d.y;
    }
    float2 inv = make_float2(rsqrtf(var.x * 0.125f + LNEPS),
                             rsqrtf(var.y * 0.125f + LNEPS));
#pragma unroll
    for (int c = 0; c < 8; c++) {
        x2[c] = make_float2((x2[c].x - mu.x) * inv.x * gm[c] + bt[c],
                            (x2[c].y - mu.y) * inv.y * gm[c] + bt[c]);
    }
}

// kA: xbar[i][c] += sum of LN(m[s,i,:]) over this thread's 8 s-rows (atomic)
__global__ __launch_bounds__(256, 4) void kA_xbar(const float* __restrict__ m,
                                                  const float* __restrict__ gamma,
                                                  const float* __restrict__ beta,
                                                  float* __restrict__ xbar) {
    int g = blockIdx.x * 256 + threadIdx.x;   // I*CH threads
    int i = g & (I - 1);
    int sc = g >> 9;
    constexpr int NIT = S / CH;
    float gm[8], bt[8];
#pragma unroll
    for (int c = 0; c < 8; c++) { gm[c] = gamma[c]; bt[c] = beta[c]; }
    float acc[8];
#pragma unroll
    for (int c = 0; c < 8; c++) acc[c] = 0.f;
    const float4* m4 = (const float4*)m;
#pragma unroll
    for (int j = 0; j < NIT; j++) {
        int row = (sc * NIT + j) * I + i;
        float x[8];
        ln8(m4[row * 2], m4[row * 2 + 1], gm, bt, x);
#pragma unroll
        for (int c = 0; c < 8; c++) acc[c] += x[c];
    }
#pragma unroll
    for (int c = 0; c < 8; c++) atomicAdd(&xbar[i * 8 + c], acc[c]);
}

// kB: per-thread recompute qk[i] from xbar, accumulate exp-sums into denom
// (atomic). sc==0 threads persist qk[i] for kC.
__global__ __launch_bounds__(256, 4) void kB_denom(const float* __restrict__ m,
                                                   const float* __restrict__ gamma,
                                                   const float* __restrict__ beta,
                                                   const float* __restrict__ Wq,
                                                   const float* __restrict__ Wk,
                                                   const float* __restrict__ xbar,
                                                   float* __restrict__ qk,
                                                   float* __restrict__ denom) {
    int g = blockIdx.x * 256 + threadIdx.x;   // I*CH threads
    int i = g & (I - 1);
    int sc = g >> 9;
    constexpr int NIT = S / CH;
    float gm[8], bt[8];
#pragma unroll
    for (int c = 0; c < 8; c++) { gm[c] = gamma[c]; bt[c] = beta[c]; }

    float xb[8];
#pragma unroll
    for (int c = 0; c < 8; c++) xb[c] = xbar[i * 8 + c];

    // qkv[h*8+c2] = (SCALE/S) * sum_c (xb . Wq_row(h,c)) * Wk[c][c2]
    float qkv[64];
#pragma unroll
    for (int j = 0; j < 64; j++) qkv[j] = 0.f;
#pragma unroll
    for (int h = 0; h < 8; h++) {
#pragma unroll
        for (int c = 0; c < 8; c++) {
            float qhc = 0.f;
#pragma unroll
            for (int c3 = 0; c3 < 8; c3++)
                qhc += xb[c3] * Wq[(h * 8 + c) * 8 + c3];   // uniform -> s_load
#pragma unroll
            for (int c2 = 0; c2 < 8; c2++)
                qkv[h * 8 + c2] += qhc * Wk[c * 8 + c2];    // uniform -> s_load
        }
    }
#pragma unroll
    for (int j = 0; j < 64; j++) qkv[j] *= (SCALE / (float)S);

    if (sc == 0) {
#pragma unroll
        for (int j = 0; j < 64; j++) qk[i * 64 + j] = qkv[j];
    }

    float acc[8];
#pragma unroll
    for (int h = 0; h < 8; h++) acc[h] = 0.f;
    const float4* m4 = (const float4*)m;
#pragma unroll
    for (int j = 0; j < NIT; j++) {
        int row = (sc * NIT + j) * I + i;
        float x[8];
        ln8(m4[row * 2], m4[row * 2 + 1], gm, bt, x);
#pragma unroll
        for (int h = 0; h < 8; h++) {
            float l = 0.f;
#pragma unroll
            for (int c2 = 0; c2 < 8; c2++) l += qkv[h * 8 + c2] * x[c2];
            acc[h] += __expf(l);
        }
    }
#pragma unroll
    for (int h = 0; h < 8; h++) atomicAdd(&denom[i * 8 + h], acc[h]);
}

// kC: final output, 2 rows per thread (one packed pair). Weights via uniform
// global loads -> scalar cache/SGPRs; no LDS.
__global__ __launch_bounds__(256, 4) void kC_out(const float* __restrict__ m,
                                                 const float* __restrict__ gamma,
                                                 const float* __restrict__ beta,
                                                 const float* __restrict__ Wv,
                                                 const float* __restrict__ Wg,
                                                 const float* __restrict__ Wo,
                                                 const float* __restrict__ bo,
                                                 const float* __restrict__ qk,
                                                 const float* __restrict__ denom,
                                                 float* __restrict__ out) {
    int g = blockIdx.x * 256 + threadIdx.x;   // I*(S/2) threads
    int i = g & (I - 1);
    int sg = g >> 9;                          // [0,512)
    float gm[8], bt[8];
#pragma unroll
    for (int c = 0; c < 8; c++) { gm[c] = gamma[c]; bt[c] = beta[c]; }

    const float4* m4 = (const float4*)m;
    int row0 = sg * I + i, row1 = (sg + 512) * I + i;
    float4 a0 = m4[row0 * 2], b0 = m4[row0 * 2 + 1];
    float4 a1 = m4[row1 * 2], b1 = m4[row1 * 2 + 1];
    float2 x2[8];
    ln8x2(a0, b0, a1, b1, gm, bt, x2);

    // v2[c] = x . Wv_row(c), packed over the row pair
    float2 v2[8];
#pragma unroll
    for (int c = 0; c < 8; c++) {
        float2 acc = make_float2(0.f, 0.f);
#pragma unroll
        for (int c2 = 0; c2 < 8; c2++)
            acc = pfma(x2[c2], Wv[c * 8 + c2], acc);        // uniform -> s_load
        v2[c] = acc;
    }

    // rden[h] = 1/denom[i][h]
    const float4* dn4 = (const float4*)denom;
    float4 d0 = dn4[i * 2], d1 = dn4[i * 2 + 1];
    float rd[8] = {__builtin_amdgcn_rcpf(d0.x), __builtin_amdgcn_rcpf(d0.y),
                   __builtin_amdgcn_rcpf(d0.z), __builtin_amdgcn_rcpf(d0.w),
                   __builtin_amdgcn_rcpf(d1.x), __builtin_amdgcn_rcpf(d1.y),
                   __builtin_amdgcn_rcpf(d1.z), __builtin_amdgcn_rcpf(d1.w)};

    float2 oacc[8];
#pragma unroll
    for (int c2 = 0; c2 < 8; c2++) oacc[c2] = make_float2(bo[c2], bo[c2]);

    const float4* qk4 = (const float4*)qk;
#pragma unroll 1
    for (int h = 0; h < 8; h++) {
        float4 q0 = qk4[i * 16 + h * 2], q1 = qk4[i * 16 + h * 2 + 1];
        float2 l2 = make_float2(0.f, 0.f);
        l2 = pfma(x2[0], q0.x, l2); l2 = pfma(x2[1], q0.y, l2);
        l2 = pfma(x2[2], q0.z, l2); l2 = pfma(x2[3], q0.w, l2);
        l2 = pfma(x2[4], q1.x, l2); l2 = pfma(x2[5], q1.y, l2);
        l2 = pfma(x2[6], q1.z, l2); l2 = pfma(x2[7], q1.w, l2);
        float2 a2 = pmuls(make_float2(__expf(l2.x), __expf(l2.y)), rd[h]);
#pragma unroll
        for (int c = 0; c < 8; c++) {
            int hc = h * 8 + c;
            float2 z2 = make_float2(0.f, 0.f);
#pragma unroll
            for (int c2 = 0; c2 < 8; c2++)
                z2 = pfma(x2[c2], Wg[hc * 8 + c2], z2);     // uniform -> s_load
            float2 g2 = make_float2(
                __builtin_amdgcn_rcpf(1.0f + __expf(-z2.x)),
                __builtin_amdgcn_rcpf(1.0f + __expf(-z2.y)));
            float2 o2 = pmul(pmul(g2, a2), v2[c]);
#pragma unroll
            for (int c2 = 0; c2 < 8; c2++)
                oacc[c2] = pfma(o2, Wo[c2 * 64 + hc], oacc[c2]); // uniform -> s_load
        }
    }

    float4* out4 = (float4*)out;
    out4[row0 * 2]     = make_float4(oacc[0].x, oacc[1].x, oacc[2].x, oacc[3].x);
    out4[row0 * 2 + 1] = make_float4(oacc[4].x, oacc[5].x, oacc[6].x, oacc[7].x);
    out4[row1 * 2]     = make_float4(oacc[0].y, oacc[1].y, oacc[2].y, oacc[3].y);
    out4[row1 * 2 + 1] = make_float4(oacc[4].y, oacc[5].y, oacc[6].y, oacc[7].y);
}

extern "C" void kernel_launch(void* const* d_in, const int* in_sizes, int n_in,
                              void* d_out, int out_size, void* d_ws, size_t ws_size,
                              hipStream_t stream) {
    const float* m     = (const float*)d_in[0];
    const float* gamma = (const float*)d_in[1];
    const float* beta  = (const float*)d_in[2];
    const float* Wq    = (const float*)d_in[3];
    const float* Wk    = (const float*)d_in[4];
    const float* Wv    = (const float*)d_in[5];
    const float* Wg    = (const float*)d_in[6];
    const float* Wo    = (const float*)d_in[7];
    const float* bo    = (const float*)d_in[8];
    float* out = (float*)d_out;

    float* ws    = (float*)d_ws;
    float* xbar  = ws;                 // I*8 = 4096 floats (atomic-accumulated)
    float* denom = ws + I * 8;         // I*8 = 4096 floats (atomic-accumulated)
    float* qk    = ws + 2 * I * 8;     // I*64 floats

    // zero only the atomic accumulators (32 KB)
    hipMemsetAsync(d_ws, 0, (size_t)(2 * I * 8) * sizeof(float), stream);

    kA_xbar<<<I * CH / 256, 256, 0, stream>>>(m, gamma, beta, xbar);
    kB_denom<<<I * CH / 256, 256, 0, stream>>>(m, gamma, beta, Wq, Wk, xbar, qk,
                                               denom);
    kC_out<<<I * (S / 2) / 256, 256, 0, stream>>>(m, gamma, beta, Wv, Wg, Wo, bo,
                                                  qk, denom, out);
}